// Round 1
// baseline (121.117 us; speedup 1.0000x reference)
//
#include <hip/hip_runtime.h>
#include <hip/hip_bf16.h>
#include <math.h>

typedef __bf16 bf16;
typedef __attribute__((ext_vector_type(8))) __bf16 bf16x8;
typedef __attribute__((ext_vector_type(4))) __bf16 bf16x4;
typedef __attribute__((ext_vector_type(4))) float f32x4;
typedef __attribute__((ext_vector_type(16))) float f32x16;
typedef __attribute__((ext_vector_type(4))) unsigned int u32x4;

constexpr int NB = 2, NH = 16, SQ = 2048, SKV = 2048, DH = 128;
constexpr int QB = 128, KVB = 64;
constexpr float SM_SCALE = 0.08838834764831845f;  // 1/sqrt(128)
constexpr float LOG2E = 1.4426950408889634f;
constexpr float DEFER_THR = 7.0f;                 // T13: p bounded by e^7

#define GLD_LDS(g, l) __builtin_amdgcn_global_load_lds( \
    (const __attribute__((address_space(1))) void*)(g), \
    (__attribute__((address_space(3))) void*)(l), 16, 0, 0)

__device__ __forceinline__ unsigned cvt_pk_bf16(float lo, float hi) {
    unsigned r;
    asm("v_cvt_pk_bf16_f32 %0, %1, %2" : "=v"(r) : "v"(lo), "v"(hi));
    return r;
}
// new a[32:63] = old b[0:31]; new b[0:31] = old a[32:63]
__device__ __forceinline__ void permswap(unsigned &a, unsigned &b) {
    asm("v_permlane32_swap_b32 %0, %1" : "+v"(a), "+v"(b));
}

// ---- pre-pass 1: K fp32 -> bf16, layout unchanged [bh][skv][d] ----
__global__ __launch_bounds__(256)
void cvt_k_kernel(const float* __restrict__ src, bf16* __restrict__ dst) {
    const size_t i = ((size_t)blockIdx.x * 256 + threadIdx.x) * 8;
    float4 a = *(const float4*)(src + i);
    float4 b = *(const float4*)(src + i + 4);
    bf16x8 f;
    f[0]=(bf16)a.x; f[1]=(bf16)a.y; f[2]=(bf16)a.z; f[3]=(bf16)a.w;
    f[4]=(bf16)b.x; f[5]=(bf16)b.y; f[6]=(bf16)b.z; f[7]=(bf16)b.w;
    *(bf16x8*)(dst + i) = f;
}

// ---- pre-pass 2: V fp32 [bh][skv][d] -> bf16 transposed [bh][d][skv] ----
__global__ __launch_bounds__(256)
void tr_v_kernel(const float* __restrict__ src, bf16* __restrict__ dst) {
    __shared__ float Tl[64][65];
    const int bh  = blockIdx.y;
    const int kv0 = (int)(blockIdx.x >> 1) * 64;
    const int d0  = (int)(blockIdx.x & 1) * 64;
    const int t   = threadIdx.x;
    const float* sp = src + (size_t)bh * SQ * DH;
#pragma unroll
    for (int i = 0; i < 4; ++i) {
        const int row = i * 16 + (t >> 4);
        const int c4  = (t & 15) * 4;
        *(float4*)&Tl[row][c4] = *(const float4*)(sp + (size_t)(kv0 + row) * DH + d0 + c4);
    }
    __syncthreads();
    bf16* dp = dst + (size_t)bh * DH * SKV;
#pragma unroll
    for (int i = 0; i < 4; ++i) {
        const int d  = i * 16 + (t >> 4);
        const int k4 = (t & 15) * 4;
        bf16x4 o;
        o[0]=(bf16)Tl[k4+0][d]; o[1]=(bf16)Tl[k4+1][d];
        o[2]=(bf16)Tl[k4+2][d]; o[3]=(bf16)Tl[k4+3][d];
        *(bf16x4*)(dp + (size_t)(d0 + d) * SKV + kv0 + k4) = o;
    }
}

// ---- main attention kernel: 32-row waves (32x32x16 MFMA), swapped-QK,
//      in-register P via cvt_pk + permlane32_swap, 4 waves / 256 threads ----
__global__ __launch_bounds__(256, 2)
void attn_fwd_kernel(const float* __restrict__ Qg, const bf16* __restrict__ Kb,
                     const bf16* __restrict__ Vb, const float* __restrict__ Bg,
                     float* __restrict__ Og, float* __restrict__ Sg)
{
    // K tile: [64 kv rows][128 d] bf16, 256B rows, 16-slot XOR swizzle (slot ^ row&15)
    __shared__ __attribute__((aligned(16))) bf16 Kl[2][KVB * DH];   // 2 x 16 KiB
    // V^T tile: 64 row-pairs [d-pair][128 elems: d-even 64 kv | d-odd 64 kv], 256B rows,
    // 16-slot XOR swizzle -> both K and V reads hit the uniform 8-bank-group b128 floor
    __shared__ __attribute__((aligned(16))) bf16 Vl[2][KVB * DH];   // 2 x 16 KiB

    const int tid = threadIdx.x;
    const int w   = tid >> 6;          // 0..3
    const int ln  = tid & 63;
    const int q5  = ln & 31;           // q-col within the wave's 32 rows
    const int hi  = ln >> 5;           // lane-half: co-owner split of each q-row
    const int l15 = ln & 15;

    const int bh = blockIdx.x;
    const int h  = bh & (NH - 1);
    // pi-permuted q-tile: CU pairs (y, y+8) -> tiles (y, 15-y), total work const
    const int qt = (blockIdx.y < 8) ? (int)blockIdx.y : 23 - (int)blockIdx.y;
    const int q0 = qt * QB;
    const int qw = q0 + w * 32;                    // wave's first q row
    const int qr = qw + q5;                        // this lane's q row

    const float slope = exp2f(-0.5f * (float)(h + 1));
    const bf16* kbase = Kb + (size_t)bh * SKV * DH;
    const bf16* vbase = Vb + (size_t)bh * DH * SKV;
    const float* bprow = Bg + (size_t)qr * SKV + 4 * hi;

    // staging: LDS dest linear (global_load_lds), source pre-swizzled (both-sides rule).
    // K: row r slot sp holds global k-slot sp^(r&15) of K[kv0+r].
    // V: rowpair r slot sp holds global (d = 2r + (sl>>3), kv-slot sl&7), sl = sp^(r&15).
    int ksrc[4], vsrc[4];
#pragma unroll
    for (int i = 0; i < 4; ++i) {
        const int seg = w * 4 + i;                 // 0..15
        const int r   = seg * 4 + (ln >> 4);       // 0..63
        const int sl  = l15 ^ (r & 15);
        ksrc[i] = r * DH + (sl << 3);
        vsrc[i] = (2 * r + (sl >> 3)) * SKV + ((sl & 7) << 3);
    }

    auto stage = [&](int kv0n, int buf) {
#pragma unroll
        for (int i = 0; i < 4; ++i)
            GLD_LDS(kbase + (size_t)kv0n * DH + ksrc[i], &Kl[buf][(w * 4 + i) * 512]);
#pragma unroll
        for (int i = 0; i < 4; ++i)
            GLD_LDS(vbase + (size_t)kv0n + vsrc[i], &Vl[buf][(w * 4 + i) * 512]);
    };

    // ---- Q fragments (pre-scaled, bf16); MFMA B operand: B[k=hi*8+j][col=q5] ----
    bf16x8 qf[8];
    {
        const float* qrow = Qg + (size_t)bh * SQ * DH + (size_t)qr * DH;
#pragma unroll
        for (int s = 0; s < 8; ++s) {
            const float* qp = qrow + s * 16 + hi * 8;
            float4 a = *(const float4*)qp;
            float4 b = *(const float4*)(qp + 4);
            bf16x8 f;
            f[0]=(bf16)(a.x*SM_SCALE); f[1]=(bf16)(a.y*SM_SCALE);
            f[2]=(bf16)(a.z*SM_SCALE); f[3]=(bf16)(a.w*SM_SCALE);
            f[4]=(bf16)(b.x*SM_SCALE); f[5]=(bf16)(b.y*SM_SCALE);
            f[6]=(bf16)(b.z*SM_SCALE); f[7]=(bf16)(b.w*SM_SCALE);
            qf[s] = f;
        }
    }

    // O^T: acc[dt] row = dt*32 + (r&3)+8*(r>>2)+4*hi, col(q) = q5
    f32x16 acc[4];
#pragma unroll
    for (int dt = 0; dt < 4; ++dt)
#pragma unroll
        for (int e = 0; e < 16; ++e) acc[dt][e] = 0.f;
    float denom = 0.f;                 // this lane-half's partial row sum
    float mrow = -INFINITY;

    const int ntile = (q0 + QB) / KVB;

    stage(0, 0);
    f32x4 bvf[2][4];                   // bias[qr][kv0 + T*32 + u*8 + 4*hi + 0..3]
#pragma unroll
    for (int T = 0; T < 2; ++T)
#pragma unroll
        for (int u = 0; u < 4; ++u)
            bvf[T][u] = *(const f32x4*)(bprow + T * 32 + u * 8);
    __syncthreads();
    int cur = 0;

    for (int t = 0; t < ntile; ++t) {
        const int kv0 = t * KVB;
        if (t + 1 < ntile) stage(kv0 + KVB, cur ^ 1);

        const bool liveTile = (kv0 <= qw + 31);    // wave-uniform: any visible kv?
        float p[2][16];
        if (liveTile) {
            // ---- S^T = K (Q*scale)^T : two 32x32 kv-tiles, 8 d-steps of 16 ----
            f32x16 s0, s1;
#pragma unroll
            for (int e = 0; e < 16; ++e) { s0[e] = 0.f; s1[e] = 0.f; }
            __builtin_amdgcn_s_setprio(1);
#pragma unroll
            for (int s = 0; s < 8; ++s) {
                const int sl = (((2 * s + hi) ^ l15) << 3);
                bf16x8 k0 = *(const bf16x8*)&Kl[cur][q5 * DH + sl];
                bf16x8 k1 = *(const bf16x8*)&Kl[cur][(32 + q5) * DH + sl];
                s0 = __builtin_amdgcn_mfma_f32_32x32x16_bf16(k0, qf[s], s0, 0, 0, 0);
                s1 = __builtin_amdgcn_mfma_f32_32x32x16_bf16(k1, qf[s], s1, 0, 0, 0);
            }
            __builtin_amdgcn_s_setprio(0);

            // lane holds S for q=qr, kv = kv0 + T*32 + 8u + v + 4*hi  (r = 4u+v)
            const int dq2 = qr - kv0 - 4 * hi;       // visible iff koffc <= dq2
            const float base2 = slope * (float)(-dq2);
            const bool needMask = (kv0 + KVB - 1 > qw);
            if (needMask) {
#pragma unroll
                for (int r = 0; r < 16; ++r) {
                    const int u = r >> 2, v = r & 3;
                    const int k0c = 8 * u + v;
                    const int k1c = 32 + 8 * u + v;
                    float x0 = s0[r] + bvf[0][u][v] + fmaf(slope, (float)k0c, base2);
                    float x1 = s1[r] + bvf[1][u][v] + fmaf(slope, (float)k1c, base2);
                    p[0][r] = (k0c > dq2) ? -INFINITY : x0;
                    p[1][r] = (k1c > dq2) ? -INFINITY : x1;
                }
            } else {
#pragma unroll
                for (int r = 0; r < 16; ++r) {
                    const int u = r >> 2, v = r & 3;
                    p[0][r] = s0[r] + bvf[0][u][v] + fmaf(slope, (float)(8*u+v), base2);
                    p[1][r] = s1[r] + bvf[1][u][v] + fmaf(slope, (float)(32+8*u+v), base2);
                }
            }

            // row max: in-lane tree + one cross-half shuffle (co-owner lane l^32)
            float mt[8];
#pragma unroll
            for (int r = 0; r < 8; ++r)
                mt[r] = fmaxf(fmaxf(p[0][r], p[0][r + 8]), fmaxf(p[1][r], p[1][r + 8]));
            float mx = fmaxf(fmaxf(fmaxf(mt[0], mt[1]), fmaxf(mt[2], mt[3])),
                             fmaxf(fmaxf(mt[4], mt[5]), fmaxf(mt[6], mt[7])));
            mx = fmaxf(mx, __shfl_xor(mx, 32));

            // T13 defer-max
            if (__any(mx > mrow + DEFER_THR)) {
                const float mn = fmaxf(mrow, mx);
                const float al = exp2f((mrow - mn) * LOG2E);
                mrow = mn;
#pragma unroll
                for (int dt = 0; dt < 4; ++dt)
#pragma unroll
                    for (int e = 0; e < 16; ++e) acc[dt][e] *= al;
                denom *= al;
            }

#pragma unroll
            for (int T = 0; T < 2; ++T)
#pragma unroll
                for (int r = 0; r < 16; ++r)
                    p[T][r] = exp2f((p[T][r] - mrow) * LOG2E);

            float st[8];
#pragma unroll
            for (int r = 0; r < 8; ++r)
                st[r] = (p[0][r] + p[0][r + 8]) + (p[1][r] + p[1][r + 8]);
            denom += ((st[0] + st[1]) + (st[2] + st[3])) +
                     ((st[4] + st[5]) + (st[6] + st[7]));
        }

        // bias prefetch for next tile (hidden under PV + next QK)
        if (t + 1 < ntile) {
#pragma unroll
            for (int T = 0; T < 2; ++T)
#pragma unroll
                for (int u = 0; u < 4; ++u)
                    bvf[T][u] = *(const f32x4*)(bprow + (kv0 + KVB) + T * 32 + u * 8);
        }

        if (liveTile) {
            // ---- PV: O^T += V^T P^T. P^T B-frag assembled in-register:
            // cvt_pk packs own-half kv pairs; permlane32_swap exchanges with co-owner.
            __builtin_amdgcn_s_setprio(1);
#pragma unroll
            for (int s2 = 0; s2 < 4; ++s2) {          // kv steps of 16
                const int T  = s2 >> 1;
                const int r0 = (s2 & 1) * 8;
                unsigned x1 = cvt_pk_bf16(p[T][r0 + 0], p[T][r0 + 1]);
                unsigned x2 = cvt_pk_bf16(p[T][r0 + 2], p[T][r0 + 3]);
                unsigned y1 = cvt_pk_bf16(p[T][r0 + 4], p[T][r0 + 5]);
                unsigned y2 = cvt_pk_bf16(p[T][r0 + 6], p[T][r0 + 7]);
                permswap(x1, y1);
                permswap(x2, y2);
                u32x4 pw; pw[0] = x1; pw[1] = x2; pw[2] = y1; pw[3] = y2;
                const bf16x8 pb = __builtin_bit_cast(bf16x8, pw);
                const int vsl = (((((q5 & 1) << 3) | (2 * s2 + hi)) ^ (q5 >> 1)) << 3);
#pragma unroll
                for (int dt = 0; dt < 4; ++dt) {
                    bf16x8 vb = *(const bf16x8*)&Vl[cur][(dt * 16 + (q5 >> 1)) * DH + vsl];
                    acc[dt] = __builtin_amdgcn_mfma_f32_32x32x16_bf16(vb, pb, acc[dt], 0, 0, 0);
                }
            }
            __builtin_amdgcn_s_setprio(0);
        }

        __syncthreads();  // drains staging vmcnt + buffer handoff
        cur ^= 1;
    }

    // ---- epilogue: combine co-owner halves, normalize, store ----
    {
        const float dtot = denom + __shfl_xor(denom, 32);
        const float inv = 1.0f / dtot;
        float* orow = Og + (size_t)bh * SQ * DH + (size_t)qr * DH;
#pragma unroll
        for (int dt = 0; dt < 4; ++dt)
#pragma unroll
            for (int u = 0; u < 4; ++u) {
                f32x4 o;
                o[0] = acc[dt][4 * u + 0] * inv;
                o[1] = acc[dt][4 * u + 1] * inv;
                o[2] = acc[dt][4 * u + 2] * inv;
                o[3] = acc[dt][4 * u + 3] * inv;
                *(f32x4*)(orow + dt * 32 + u * 8 + hi * 4) = o;
            }
        if (hi == 0)
            Sg[(size_t)bh * SQ + qr] = mrow + logf(dtot);
    }
}

extern "C" void kernel_launch(void* const* d_in, const int* in_sizes, int n_in,
                              void* d_out, int out_size, void* d_ws, size_t ws_size,
                              hipStream_t stream) {
    const float* Q = (const float*)d_in[0];
    const float* K = (const float*)d_in[1];
    const float* V = (const float*)d_in[2];
    const float* B = (const float*)d_in[3];
    float* O     = (float*)d_out;
    float* Stats = O + (size_t)NB * NH * SQ * DH;

    const size_t nkv = (size_t)NB * NH * SKV * DH;
    bf16* Kb = (bf16*)d_ws;
    bf16* Vt = Kb + nkv;

    cvt_k_kernel<<<(int)(nkv / (256 * 8)), 256, 0, stream>>>(K, Kb);
    tr_v_kernel<<<dim3(64, NB * NH), 256, 0, stream>>>(V, Vt);

    dim3 grid(NB * NH, SQ / QB);   // x = bh (CU pairing pairs y,y+8 -> balanced)
    attn_fwd_kernel<<<grid, 256, 0, stream>>>(Q, Kb, Vt, B, O, Stats);
}